// Round 7
// baseline (168.313 us; speedup 1.0000x reference)
//
#include <hip/hip_runtime.h>

#define N_NODES 100000
#define N_EDGES 1250000
#define IN_CH 128
#define OUT_CH 64

#define NPB 128           // nodes per bin; bin = row >> 7
#define ACCS2 33          // u64 acc row stride (pad): 128*33*8 = 33792 B LDS
#define NBINS 782         // ceil(100000/128)
#define LSTRIDE 783       // lscan2d row stride (NBINS+1 entries per sort block)
#define NB1 384           // sort blocks (srec 26KB -> 4 blocks/CU)
#define B1T 512
#define CH1 ((N_EDGES + NB1 - 1) / NB1)   // 3256 edges per sort block
#define MAXU ((CH1 + B1T - 1) / B1T)      // 7 edges cached per thread
#define GEMM_BLOCKS ((N_NODES + 127) / 128)  // 782 gemm blocks @ 128 nodes

// fixed-point: q = rn(val * sc), biased by 2^23 per contribution (sign-safe,
// ulp(2^23)=1.0; lo-half total stays << 2^32 at max ~45 edges/row)
#define QSCALE 8192.0f
#define QBIAS_F 8388608.0f
#define QBIAS_U 8388608u
#define INV_QSCALE 1.220703125e-4f   // 2^-13
#define SCALE_DEG 33554432.0f        // 2^25 fixed-point for degree accum
#define INV_SCALE_DEG 2.9802322387695312e-08f

typedef __attribute__((ext_vector_type(8))) short short8;
typedef __attribute__((ext_vector_type(4))) float f32x4;

// round-to-nearest-even f32 -> bf16
__device__ inline unsigned int f2bf(float f) {
    unsigned int u = __float_as_uint(f);
    unsigned int r = ((u >> 16) & 1u) + 0x7FFFu;
    return (u + r) >> 16;
}
__device__ inline float bf_lo(unsigned int p) { return __uint_as_float(p << 16); }
__device__ inline float bf_hi(unsigned int p) { return __uint_as_float(p & 0xFFFF0000u); }

// biased fixed-point quantize of one packed bf16x2, scaled by sc = QSCALE*dis_col
__device__ inline unsigned long long qpacks(unsigned int p, float sc) {
    unsigned int lo = (unsigned int)__float2int_rn(fmaf(bf_lo(p), sc, QBIAS_F));
    unsigned int hi = (unsigned int)__float2int_rn(fmaf(bf_hi(p), sc, QBIAS_F));
    return ((unsigned long long)hi << 32) | (unsigned long long)lo;
}

// ---------------------------------------------------------------------------
// Dispatch 1: blocks [0,NB1) = LDS counting sort of this block's edge chunk
// by bin (row>>7); ALL global writes coalesced (R0-R3 lesson: scattered 8B
// brec stores were a ~25us structural tail). Blocks [NB1,NB1+2) = W -> Wb
// bf16 MFMA-fragment conversion.
// ---------------------------------------------------------------------------
__global__ __launch_bounds__(B1T) void sort_kernel(const int* __restrict__ ei,
                                                   const float* __restrict__ ew,
                                                   const float* __restrict__ W,
                                                   unsigned int* __restrict__ Wb,
                                                   int* __restrict__ lscan2d,
                                                   int2* __restrict__ brec) {
    __shared__ int2 srec[CH1];        // 26048 B sorted run
    __shared__ int shist[NBINS];      // hist, then reused as rank counters
    __shared__ int sscan[NBINS + 2];  // exclusive scan (incl. total at [NBINS])
    __shared__ int ssum[256];         // chunk sums for scan
    const int tid = threadIdx.x;

    if (blockIdx.x >= NB1) {
        int g = (blockIdx.x - NB1) * B1T + tid;   // 1024 lane-slots
        if (g < 1024) {
            int c = g >> 8;
            int t4 = (g >> 6) & 3;
            int l = g & 63;
            int q = l >> 4, r15 = l & 15;
            unsigned int o[4];
#pragma unroll
            for (int jj = 0; jj < 4; ++jj) {
                float f0 = W[(c * 32 + q * 8 + 2 * jj)     * OUT_CH + t4 * 16 + r15];
                float f1 = W[(c * 32 + q * 8 + 2 * jj + 1) * OUT_CH + t4 * 16 + r15];
                o[jj] = f2bf(f0) | (f2bf(f1) << 16);
            }
            *(uint4*)(Wb + (size_t)g * 4) = make_uint4(o[0], o[1], o[2], o[3]);
        }
        return;
    }

    // ----- sort -----
    for (int i = tid; i < NBINS; i += B1T) shist[i] = 0;
    __syncthreads();

    const int e0 = blockIdx.x * CH1;
    const int total = (e0 + CH1 < N_EDGES) ? CH1 : N_EDGES - e0;

    int rowv[MAXU], colv[MAXU];
    float wv[MAXU];
#pragma unroll
    for (int u = 0; u < MAXU; ++u) {
        int e = e0 + tid + u * B1T;
        bool ok = (tid + u * B1T) < total;
        rowv[u] = ok ? ei[e] : -1;
        colv[u] = ok ? ei[N_EDGES + e] : 0;
        wv[u]   = ok ? ew[e] : 0.0f;
        if (ok) atomicAdd(&shist[rowv[u] >> 7], 1);
    }
    __syncthreads();

    // block-local exclusive scan: shist[0..NBINS) -> sscan[0..NBINS]
    int a0 = 0, a1 = 0, a2 = 0, a3 = 0, part = 0;
    const int b0 = tid * 4;
    if (tid < 256) {
        a0 = (b0 + 0 < NBINS) ? shist[b0 + 0] : 0;
        a1 = (b0 + 1 < NBINS) ? shist[b0 + 1] : 0;
        a2 = (b0 + 2 < NBINS) ? shist[b0 + 2] : 0;
        a3 = (b0 + 3 < NBINS) ? shist[b0 + 3] : 0;
        part = a0 + a1 + a2 + a3;
        ssum[tid] = part;
    }
    __syncthreads();
#pragma unroll
    for (int d = 1; d < 256; d <<= 1) {
        int add = 0;
        if (tid >= d && tid < 256) add = ssum[tid - d];
        __syncthreads();
        if (tid < 256) ssum[tid] += add;
        __syncthreads();
    }
    if (tid < 256) {
        int base = ssum[tid] - part;   // exclusive chunk base
        if (b0 + 0 <= NBINS) sscan[b0 + 0] = base;
        if (b0 + 1 <= NBINS) sscan[b0 + 1] = base + a0;
        if (b0 + 2 <= NBINS) sscan[b0 + 2] = base + a0 + a1;
        if (b0 + 3 <= NBINS) sscan[b0 + 3] = base + a0 + a1 + a2;
    }
    __syncthreads();

    // reuse shist as rank counters
    for (int i = tid; i < NBINS; i += B1T) shist[i] = 0;
    __syncthreads();

    // scatter registers -> LDS sorted buffer (exact slots, memory-safe by
    // construction: sscan[bb]+rk < total <= CH1)
#pragma unroll
    for (int u = 0; u < MAXU; ++u) {
        if (rowv[u] >= 0) {
            int bb = rowv[u] >> 7;
            int rk = atomicAdd(&shist[bb], 1);
            srec[sscan[bb] + rk] = make_int2(((rowv[u] & 127) << 17) | colv[u],
                                             __float_as_int(wv[u]));
        }
    }
    __syncthreads();

    // coalesced streaming writeout
    for (int i = tid; i < total; i += B1T) brec[e0 + i] = srec[i];
    int* lrow = lscan2d + blockIdx.x * LSTRIDE;
    for (int i = tid; i <= NBINS; i += B1T) lrow[i] = sscan[i];
}

// ---------------------------------------------------------------------------
// Dispatch 2 (heterogeneous):
//   blocks [0, GEMM_BLOCKS)  : bf16-MFMA GEMM hs = bf16(x @ W), UNSCALED.
//   blocks [GEMM_BLOCKS, +NBINS): degpass-lite — thread t walks sorted
//      segment t of this bin (brec contiguous runs); ONE packed u64 LDS
//      atomic per record (lo = weighted-deg fixed-point, hi = count).
//      Emits dis[] and qcnt[] only. ~4-5 us of work, hides under the GEMM.
// (R6 post-mortem: heterogeneous halves overlap poorly (~additive), so the
// co-runner must be SMALL. binprep's arena/staging work is deleted outright —
// gather now fetches records straight from the sorted segments.)
// ---------------------------------------------------------------------------
__global__ __launch_bounds__(512) void deg_gemm_kernel(const float* __restrict__ x,
                                                       const unsigned int* __restrict__ Wb,
                                                       const int* __restrict__ lscan2d,
                                                       const int2* __restrict__ brec,
                                                       float* __restrict__ dis,
                                                       int* __restrict__ qcnt,
                                                       unsigned int* __restrict__ hs) {
    const int tid = threadIdx.x;

    if (blockIdx.x < GEMM_BLOCKS) {
        // ----- GEMM: 128 nodes per block, 8 waves x 16 rows -----
        const int blk  = blockIdx.x;
        const int w    = tid >> 6;
        const int lane = tid & 63;
        const int q    = lane >> 4, r15 = lane & 15;
        const int node = blk * 128 + w * 16 + r15;
        const int nl   = (node < N_NODES) ? node : N_NODES - 1;   // clamp loads
        const float* xrow = x + (size_t)nl * IN_CH;

        f32x4 acc[4];
#pragma unroll
        for (int t = 0; t < 4; ++t) acc[t] = (f32x4){0.f, 0.f, 0.f, 0.f};

#pragma unroll
        for (int c = 0; c < 4; ++c) {
            float4 xa = *(const float4*)(xrow + c * 32 + q * 8);
            float4 xb = *(const float4*)(xrow + c * 32 + q * 8 + 4);
            short8 bfrag;
            bfrag[0] = (short)f2bf(xa.x); bfrag[1] = (short)f2bf(xa.y);
            bfrag[2] = (short)f2bf(xa.z); bfrag[3] = (short)f2bf(xa.w);
            bfrag[4] = (short)f2bf(xb.x); bfrag[5] = (short)f2bf(xb.y);
            bfrag[6] = (short)f2bf(xb.z); bfrag[7] = (short)f2bf(xb.w);
#pragma unroll
            for (int t = 0; t < 4; ++t) {
                short8 afrag = *(const short8*)(Wb + (size_t)((c * 4 + t) * 64 + lane) * 4);
                acc[t] = __builtin_amdgcn_mfma_f32_16x16x32_bf16(afrag, bfrag, acc[t], 0, 0, 0);
            }
        }

        if (node < N_NODES) {
#pragma unroll
            for (int t = 0; t < 4; ++t) {
                unsigned int p0 = f2bf(acc[t][0]) | (f2bf(acc[t][1]) << 16);
                unsigned int p1 = f2bf(acc[t][2]) | (f2bf(acc[t][3]) << 16);
                *(uint2*)(hs + (size_t)node * 32 + t * 8 + q * 2) = make_uint2(p0, p1);
            }
        }
    } else {
        // ----- degpass-lite -----
        __shared__ unsigned long long degcnt[NPB];  // lo: fp wdeg, hi: count
        const int b = blockIdx.x - GEMM_BLOCKS;
        if (tid < NPB) degcnt[tid] = 0ull;
        __syncthreads();
        if (tid < NB1) {
            int st = lscan2d[tid * LSTRIDE + b];
            int en = lscan2d[tid * LSTRIDE + b + 1];
            const int2* seg = brec + (size_t)tid * CH1;
            for (int j = st; j < en; ++j) {
                int2 r = seg[j];
                unsigned int qd = (unsigned int)__float2int_rn(__int_as_float(r.y) * SCALE_DEG);
                atomicAdd(&degcnt[r.x >> 17], (1ull << 32) | (unsigned long long)qd);
            }
        }
        __syncthreads();
        if (tid < NPB) {
            int node = b * NPB + tid;
            if (node < N_NODES) {
                unsigned long long dc = degcnt[tid];
                float d = (float)(unsigned int)dc * INV_SCALE_DEG;
                dis[node]  = (d == 0.0f) ? 0.0f : (1.0f / sqrtf(d));
                qcnt[node] = (int)(dc >> 32);
            }
        }
    }
}

// ---------------------------------------------------------------------------
// Bin-gather: one 512-thread block per 128-node bin. Records fetched DIRECTLY
// from the bin's NB1 sorted segments (no compacted arena, no binprep pass):
// preamble scans segment lengths (inclusive Hillis-Steele over NB1), then
// each 8-lane group owns a balanced flat-index range and walks it with an
// O(1)-amortized incremental segment cursor (one preamble binary search; the
// per-record advance is a rarely-taken while). All fetches are broadcast
// across the 8-lane group. LDS = 33.8K acc + 3K scan -> 4 blocks/CU kept.
// u64-packed LDS atomics (2 biased fixed-point channels per ds_add_u64);
// 4-deep pipeline against the L3-latency-bound hs gather.
// ---------------------------------------------------------------------------
__global__ __launch_bounds__(512) void gather_kernel(const int* __restrict__ lscan2d,
                                                     const int2* __restrict__ brec,
                                                     const uint4* __restrict__ hs, // 8/row
                                                     const float* __restrict__ dis,
                                                     const int* __restrict__ qcnt,
                                                     const float* __restrict__ b,
                                                     float* __restrict__ out) {
    __shared__ unsigned long long acc[NPB * ACCS2];   // 33792 B
    __shared__ int sst[NB1];
    __shared__ int soff[NB1];                         // inclusive scan of lens
    const int tid = threadIdx.x;
    const int blk = blockIdx.x;
    for (int k = tid; k < NPB * ACCS2; k += 512) acc[k] = 0ull;
    if (tid < NB1) {
        int st = lscan2d[tid * LSTRIDE + blk];
        int en = lscan2d[tid * LSTRIDE + blk + 1];
        sst[tid]  = st;
        soff[tid] = en - st;
    }
    __syncthreads();
#pragma unroll
    for (int d = 1; d < NB1; d <<= 1) {   // inclusive Hillis-Steele scan
        int add = 0;
        if (tid >= d && tid < NB1) add = soff[tid - d];
        __syncthreads();
        if (tid < NB1) soff[tid] += add;
        __syncthreads();
    }
    const int m = soff[NB1 - 1];

    const int wid = tid >> 6, lane = tid & 63;
    const int grp = wid * 8 + (lane >> 3);   // 0..63: 8-lane group id
    const int l8  = lane & 7;
    const int per = (m + 63) >> 6;
    const int p0  = grp * per;
    const int p1  = (p0 + per < m) ? p0 + per : m;

    // initial cursor: smallest lo with soff[lo] > p0
    int lo = 0;
    if (p0 < m) {
        int hi = NB1 - 1;
        while (lo < hi) {
            int mid = (lo + hi) >> 1;
            if (soff[mid] > p0) hi = mid; else lo = mid + 1;
        }
    }
    int excl = (lo == 0) ? 0 : soff[lo - 1];

    for (int p = p0; p < p1; p += 4) {
        bool ok[4];
        int rec[4];
        uint4 hv[4];
        float sc[4];
        int plo = lo, pexcl = excl;
#pragma unroll
        for (int s = 0; s < 4; ++s) {
            int pp = p + s;
            ok[s] = pp < p1;
            rec[s] = 0;
            if (ok[s]) {
                while (pp >= soff[plo]) { pexcl = soff[plo]; ++plo; }
                rec[s] = brec[(size_t)plo * CH1 + sst[plo] + (pp - pexcl)].x;
            }
        }
        lo = plo; excl = pexcl;
#pragma unroll
        for (int s = 0; s < 4; ++s) {
            hv[s] = ok[s] ? hs[(size_t)(rec[s] & 0x1FFFF) * 8 + l8]
                          : make_uint4(0, 0, 0, 0);
            sc[s] = ok[s] ? QSCALE * dis[rec[s] & 0x1FFFF] : 0.0f;
        }
#pragma unroll
        for (int s = 0; s < 4; ++s) {
            if (ok[s]) {
                int ba = (rec[s] >> 17) * ACCS2 + 4 * l8;
                atomicAdd(&acc[ba + 0], qpacks(hv[s].x, sc[s]));
                atomicAdd(&acc[ba + 1], qpacks(hv[s].y, sc[s]));
                atomicAdd(&acc[ba + 2], qpacks(hv[s].z, sc[s]));
                atomicAdd(&acc[ba + 3], qpacks(hv[s].w, sc[s]));
            }
        }
    }
    __syncthreads();

    // writeout: wave w handles node-locals [w*16, w*16+16); lane = channel c.
    // channel c lives in 32-bit half (c&1) of u64 slot (c>>1). Bias removal
    // uses the per-node edge count qcnt (degpass).
    const unsigned int* acc32 = (const unsigned int*)acc;
    float bc = b[lane];
    int half = lane & 1, slot = lane >> 1;
#pragma unroll 4
    for (int r = 0; r < 16; ++r) {
        int nl = wid * 16 + r;
        int node = blk * NPB + nl;
        if (node < N_NODES) {
            unsigned int raw = acc32[(nl * ACCS2 + slot) * 2 + half];
            int qsum = (int)(raw - (unsigned int)qcnt[node] * QBIAS_U);
            float di = dis[node] * INV_QSCALE;
            out[(size_t)node * OUT_CH + lane] = (float)qsum * di + bc;
        }
    }
}

extern "C" void kernel_launch(void* const* d_in, const int* in_sizes, int n_in,
                              void* d_out, int out_size, void* d_ws, size_t ws_size,
                              hipStream_t stream) {
    const float* x  = (const float*)d_in[0];
    const int*   ei = (const int*)d_in[1];
    const float* ew = (const float*)d_in[2];
    const float* W  = (const float*)d_in[3];
    const float* b  = (const float*)d_in[4];
    float* out = (float*)d_out;

    // Workspace layout (4-byte units)
    unsigned int* hs = (unsigned int*)d_ws;                   // N*32 uints (12.8 MB)
    unsigned int* Wb = hs + (size_t)N_NODES * 32;             // 4096 uints
    int* lscan2d = (int*)(Wb + 4096);                         // NB1*LSTRIDE ints (1.2 MB)
    float* dis   = (float*)(lscan2d + (size_t)NB1 * LSTRIDE); // N floats
    int* qcnt    = (int*)(dis + N_NODES);                     // N ints
    int2* brec   = (int2*)(qcnt + N_NODES);                   // NB1*CH1 int2 (10 MB)
    (void)ws_size; (void)in_sizes; (void)n_in; (void)out_size;

    sort_kernel<<<NB1 + 2, B1T, 0, stream>>>(ei, ew, W, Wb, lscan2d, brec);
    deg_gemm_kernel<<<GEMM_BLOCKS + NBINS, 512, 0, stream>>>(x, Wb, lscan2d, brec,
                                                             dis, qcnt, hs);
    gather_kernel<<<NBINS, 512, 0, stream>>>(lscan2d, brec, (const uint4*)hs,
                                             dis, qcnt, b, out);
}

// Round 8
// 161.130 us; speedup vs baseline: 1.0446x; 1.0446x over previous
//
#include <hip/hip_runtime.h>

#define N_NODES 100000
#define N_EDGES 1250000
#define IN_CH 128
#define OUT_CH 64

#define NPB 128           // nodes per bin; bin = row >> 7
#define ACCS2 33          // u64 acc row stride (pad): 128*33*8 = 33792 B LDS
#define NBINS 782         // ceil(100000/128)
#define LSTRIDE 783       // lscan2d row stride (NBINS+1 entries per sort block)
#define RECCAP 2048       // bin arena cap (mean 1598, sigma ~40, +11 sigma)
#define NB1 384           // sort blocks (srec 26KB -> 4 blocks/CU)
#define B1T 512
#define CH1 ((N_EDGES + NB1 - 1) / NB1)   // 3256 edges per sort block
#define MAXU ((CH1 + B1T - 1) / B1T)      // 7 edges cached per thread
#define NG4 ((NBINS + 3) / 4)             // 196 prep blocks (4 bins each)
#define GEMM_BLOCKS ((N_NODES + 127) / 128)  // 782 gemm blocks @ 128 nodes

// fixed-point: q = rn(val * sc), biased by 2^23 per contribution (sign-safe,
// ulp(2^23)=1.0; lo-half total stays << 2^32 at max ~45 edges/row)
#define QSCALE 8192.0f
#define QBIAS_F 8388608.0f
#define QBIAS_U 8388608u
#define INV_QSCALE 1.220703125e-4f   // 2^-13
#define SCALE_DEG 33554432.0f        // 2^25 fixed-point for degree accum
#define INV_SCALE_DEG 2.9802322387695312e-08f

typedef __attribute__((ext_vector_type(8))) short short8;
typedef __attribute__((ext_vector_type(4))) float f32x4;

// round-to-nearest-even f32 -> bf16
__device__ inline unsigned int f2bf(float f) {
    unsigned int u = __float_as_uint(f);
    unsigned int r = ((u >> 16) & 1u) + 0x7FFFu;
    return (u + r) >> 16;
}
__device__ inline float bf_lo(unsigned int p) { return __uint_as_float(p << 16); }
__device__ inline float bf_hi(unsigned int p) { return __uint_as_float(p & 0xFFFF0000u); }

// biased fixed-point quantize of one packed bf16x2, scaled by sc = QSCALE*dis_col
__device__ inline unsigned long long qpacks(unsigned int p, float sc) {
    unsigned int lo = (unsigned int)__float2int_rn(fmaf(bf_lo(p), sc, QBIAS_F));
    unsigned int hi = (unsigned int)__float2int_rn(fmaf(bf_hi(p), sc, QBIAS_F));
    return ((unsigned long long)hi << 32) | (unsigned long long)lo;
}

// ---------------------------------------------------------------------------
// Dispatch 1: blocks [0,NB1) = LDS counting sort of this block's edge chunk
// by bin (row>>7); ALL global writes coalesced (R0-R3 lesson). Blocks
// [NB1,NB1+2) = W -> Wb bf16 MFMA-fragment conversion.
// ---------------------------------------------------------------------------
__global__ __launch_bounds__(B1T) void sort_kernel(const int* __restrict__ ei,
                                                   const float* __restrict__ ew,
                                                   const float* __restrict__ W,
                                                   unsigned int* __restrict__ Wb,
                                                   int* __restrict__ lscan2d,
                                                   int2* __restrict__ brec) {
    __shared__ int2 srec[CH1];        // 26048 B sorted run
    __shared__ int shist[NBINS];      // hist, then reused as rank counters
    __shared__ int sscan[NBINS + 2];  // exclusive scan (incl. total at [NBINS])
    __shared__ int ssum[256];         // chunk sums for scan
    const int tid = threadIdx.x;

    if (blockIdx.x >= NB1) {
        int g = (blockIdx.x - NB1) * B1T + tid;   // 1024 lane-slots
        if (g < 1024) {
            int c = g >> 8;
            int t4 = (g >> 6) & 3;
            int l = g & 63;
            int q = l >> 4, r15 = l & 15;
            unsigned int o[4];
#pragma unroll
            for (int jj = 0; jj < 4; ++jj) {
                float f0 = W[(c * 32 + q * 8 + 2 * jj)     * OUT_CH + t4 * 16 + r15];
                float f1 = W[(c * 32 + q * 8 + 2 * jj + 1) * OUT_CH + t4 * 16 + r15];
                o[jj] = f2bf(f0) | (f2bf(f1) << 16);
            }
            *(uint4*)(Wb + (size_t)g * 4) = make_uint4(o[0], o[1], o[2], o[3]);
        }
        return;
    }

    // ----- sort -----
    for (int i = tid; i < NBINS; i += B1T) shist[i] = 0;
    __syncthreads();

    const int e0 = blockIdx.x * CH1;
    const int total = (e0 + CH1 < N_EDGES) ? CH1 : N_EDGES - e0;

    int rowv[MAXU], colv[MAXU];
    float wv[MAXU];
#pragma unroll
    for (int u = 0; u < MAXU; ++u) {
        int e = e0 + tid + u * B1T;
        bool ok = (tid + u * B1T) < total;
        rowv[u] = ok ? ei[e] : -1;
        colv[u] = ok ? ei[N_EDGES + e] : 0;
        wv[u]   = ok ? ew[e] : 0.0f;
        if (ok) atomicAdd(&shist[rowv[u] >> 7], 1);
    }
    __syncthreads();

    // block-local exclusive scan: shist[0..NBINS) -> sscan[0..NBINS]
    int a0 = 0, a1 = 0, a2 = 0, a3 = 0, part = 0;
    const int b0 = tid * 4;
    if (tid < 256) {
        a0 = (b0 + 0 < NBINS) ? shist[b0 + 0] : 0;
        a1 = (b0 + 1 < NBINS) ? shist[b0 + 1] : 0;
        a2 = (b0 + 2 < NBINS) ? shist[b0 + 2] : 0;
        a3 = (b0 + 3 < NBINS) ? shist[b0 + 3] : 0;
        part = a0 + a1 + a2 + a3;
        ssum[tid] = part;
    }
    __syncthreads();
#pragma unroll
    for (int d = 1; d < 256; d <<= 1) {
        int add = 0;
        if (tid >= d && tid < 256) add = ssum[tid - d];
        __syncthreads();
        if (tid < 256) ssum[tid] += add;
        __syncthreads();
    }
    if (tid < 256) {
        int base = ssum[tid] - part;   // exclusive chunk base
        if (b0 + 0 <= NBINS) sscan[b0 + 0] = base;
        if (b0 + 1 <= NBINS) sscan[b0 + 1] = base + a0;
        if (b0 + 2 <= NBINS) sscan[b0 + 2] = base + a0 + a1;
        if (b0 + 3 <= NBINS) sscan[b0 + 3] = base + a0 + a1 + a2;
    }
    __syncthreads();

    // reuse shist as rank counters
    for (int i = tid; i < NBINS; i += B1T) shist[i] = 0;
    __syncthreads();

    // scatter registers -> LDS sorted buffer (exact slots, memory-safe by
    // construction: sscan[bb]+rk < total <= CH1)
#pragma unroll
    for (int u = 0; u < MAXU; ++u) {
        if (rowv[u] >= 0) {
            int bb = rowv[u] >> 7;
            int rk = atomicAdd(&shist[bb], 1);
            srec[sscan[bb] + rk] = make_int2(((rowv[u] & 127) << 17) | colv[u],
                                             __float_as_int(wv[u]));
        }
    }
    __syncthreads();

    // coalesced streaming writeout
    for (int i = tid; i < total; i += B1T) brec[e0 + i] = srec[i];
    int* lrow = lscan2d + blockIdx.x * LSTRIDE;
    for (int i = tid; i <= NBINS; i += B1T) lrow[i] = sscan[i];
}

// ---------------------------------------------------------------------------
// Dispatch 2 (heterogeneous):
//   blocks [0, NG4)          : binprep4 — FOUR bins per block (R7 lesson: the
//      per-bin lscan column read was ~19 MB of 64B-line waste; the 5 column
//      boundaries for bins b..b+4 sit in ONE line per thread -> ~4.7 MB, and
//      scan/walk overheads amortize 4x). Per sub-bin: scan of NB1 segment
//      lengths, strided walk with per-record binary search (consecutive flat
//      indices across consecutive threads -> near-coalesced brec reads),
//      LDS-staged coalesced brec2 writeout, fused packed u64 deg/count
//      atomics. Emits brec2, dis, qcnt, mtot.
//   blocks [NG4, +GEMM_BLOCKS): bf16-MFMA GEMM hs = bf16(x @ W), UNSCALED.
// (Co-dispatch halves run ~additively — R5/R6/R7 — so the win must come from
//  the prep half itself shrinking, not from pairing.)
// ---------------------------------------------------------------------------
__global__ __launch_bounds__(512) void prep_gemm_kernel(const float* __restrict__ x,
                                                        const unsigned int* __restrict__ Wb,
                                                        const int* __restrict__ lscan2d,
                                                        const int2* __restrict__ brec,
                                                        int* __restrict__ brec2,
                                                        float* __restrict__ dis,
                                                        int* __restrict__ qcnt,
                                                        int* __restrict__ mtot,
                                                        unsigned int* __restrict__ hs) {
    const int tid = threadIdx.x;

    if (blockIdx.x < NG4) {
        // ----- binprep4 -----
        __shared__ int lsc[NB1][6];       // 5 column boundaries (pad to 6)
        __shared__ int soff[NB1];         // inclusive scan of seg lens
        __shared__ int recs[RECCAP];      // staged 4B records
        __shared__ unsigned long long degcnt[512];  // lo: fp wdeg, hi: count
        const int b0bin = blockIdx.x * 4;

        degcnt[tid] = 0ull;
        if (tid < NB1) {
            const int* lrow = lscan2d + tid * LSTRIDE;
#pragma unroll
            for (int j = 0; j < 5; ++j) {
                int bi = b0bin + j;
                lsc[tid][j] = lrow[(bi < NBINS) ? bi : NBINS];
            }
        }
        __syncthreads();

        for (int j = 0; j < 4; ++j) {
            int bin = b0bin + j;
            if (bin >= NBINS) break;
            if (tid < NB1) soff[tid] = lsc[tid][j + 1] - lsc[tid][j];
            __syncthreads();
#pragma unroll
            for (int d = 1; d < NB1; d <<= 1) {   // inclusive Hillis-Steele
                int add = 0;
                if (tid >= d && tid < NB1) add = soff[tid - d];
                __syncthreads();
                if (tid < NB1) soff[tid] += add;
                __syncthreads();
            }
            const int m = soff[NB1 - 1];
            const int mc = (m < RECCAP) ? m : RECCAP;

            for (int p = tid; p < m; p += 512) {
                // smallest lo with soff[lo] > p
                int lo = 0, hi = NB1 - 1;
                while (lo < hi) {
                    int mid = (lo + hi) >> 1;
                    if (soff[mid] > p) hi = mid; else lo = mid + 1;
                }
                int excl = (lo == 0) ? 0 : soff[lo - 1];
                int2 r = brec[(size_t)lo * CH1 + lsc[lo][j] + (p - excl)];
                if (p < RECCAP) recs[p] = r.x;
                unsigned int qd =
                    (unsigned int)__float2int_rn(__int_as_float(r.y) * SCALE_DEG);
                atomicAdd(&degcnt[j * NPB + (r.x >> 17)],
                          (1ull << 32) | (unsigned long long)qd);
            }
            __syncthreads();

            for (int p = tid; p < mc; p += 512)   // coalesced writeout
                brec2[(size_t)bin * RECCAP + p] = recs[p];
            if (tid == 0) mtot[bin] = mc;
            __syncthreads();   // recs/soff reused next sub-bin
        }

        // dis/qcnt writeout: 512 nodes, coalesced
        int node = b0bin * NPB + tid;
        if ((b0bin + (tid >> 7)) < NBINS && node < N_NODES) {
            unsigned long long dc = degcnt[tid];
            float d = (float)(unsigned int)dc * INV_SCALE_DEG;
            dis[node]  = (d == 0.0f) ? 0.0f : (1.0f / sqrtf(d));
            qcnt[node] = (int)(dc >> 32);
        }
    } else {
        // ----- GEMM: 128 nodes per block, 8 waves x 16 rows -----
        const int blk  = blockIdx.x - NG4;
        const int w    = tid >> 6;
        const int lane = tid & 63;
        const int q    = lane >> 4, r15 = lane & 15;
        const int node = blk * 128 + w * 16 + r15;
        const int nl   = (node < N_NODES) ? node : N_NODES - 1;   // clamp loads
        const float* xrow = x + (size_t)nl * IN_CH;

        f32x4 acc[4];
#pragma unroll
        for (int t = 0; t < 4; ++t) acc[t] = (f32x4){0.f, 0.f, 0.f, 0.f};

#pragma unroll
        for (int c = 0; c < 4; ++c) {
            float4 xa = *(const float4*)(xrow + c * 32 + q * 8);
            float4 xb = *(const float4*)(xrow + c * 32 + q * 8 + 4);
            short8 bfrag;
            bfrag[0] = (short)f2bf(xa.x); bfrag[1] = (short)f2bf(xa.y);
            bfrag[2] = (short)f2bf(xa.z); bfrag[3] = (short)f2bf(xa.w);
            bfrag[4] = (short)f2bf(xb.x); bfrag[5] = (short)f2bf(xb.y);
            bfrag[6] = (short)f2bf(xb.z); bfrag[7] = (short)f2bf(xb.w);
#pragma unroll
            for (int t = 0; t < 4; ++t) {
                short8 afrag = *(const short8*)(Wb + (size_t)((c * 4 + t) * 64 + lane) * 4);
                acc[t] = __builtin_amdgcn_mfma_f32_16x16x32_bf16(afrag, bfrag, acc[t], 0, 0, 0);
            }
        }

        if (node < N_NODES) {
#pragma unroll
            for (int t = 0; t < 4; ++t) {
                unsigned int p0 = f2bf(acc[t][0]) | (f2bf(acc[t][1]) << 16);
                unsigned int p1 = f2bf(acc[t][2]) | (f2bf(acc[t][3]) << 16);
                *(uint2*)(hs + (size_t)node * 32 + t * 8 + q * 2) = make_uint2(p0, p1);
            }
        }
    }
}

// ---------------------------------------------------------------------------
// Bin-gather: one 512-thread block per 128-node bin. Lean (R4/R7 lesson: no
// preamble, dense bin-contiguous arena for read locality; LDS 33.8 KB ->
// 4 blocks/CU). u64-packed LDS atomics (2 biased fixed-point channels per
// ds_add_u64); 4-deep edge pipeline against the L3-latency-bound hs gather.
// ---------------------------------------------------------------------------
__global__ __launch_bounds__(512) void gather_kernel(const int* __restrict__ mtot,
                                                     const int* __restrict__ brec2,
                                                     const uint4* __restrict__ hs, // 8/row
                                                     const float* __restrict__ dis,
                                                     const int* __restrict__ qcnt,
                                                     const float* __restrict__ b,
                                                     float* __restrict__ out) {
    __shared__ unsigned long long acc[NPB * ACCS2];   // 33792 B
    const int tid = threadIdx.x;
    const int blk = blockIdx.x;
    for (int k = tid; k < NPB * ACCS2; k += 512) acc[k] = 0ull;
    __syncthreads();

    const int m = mtot[blk];
    const int rbase = blk * RECCAP;

    const int wid = tid >> 6, lane = tid & 63;
    const int sub = lane >> 3, l8 = lane & 7;

    for (int j0 = wid * 32; j0 < m; j0 += 256) {
        bool ok[4];
        int rec[4];
        uint4 p[4];
        float sc[4];
#pragma unroll
        for (int s = 0; s < 4; ++s) {
            int jj = j0 + 8 * s + sub;
            ok[s] = jj < m;
            rec[s] = ok[s] ? brec2[rbase + jj] : 0;
        }
#pragma unroll
        for (int s = 0; s < 4; ++s) {
            p[s] = ok[s] ? hs[(size_t)(rec[s] & 0x1FFFF) * 8 + l8]
                         : make_uint4(0, 0, 0, 0);
            sc[s] = ok[s] ? QSCALE * dis[rec[s] & 0x1FFFF] : 0.0f;
        }
#pragma unroll
        for (int s = 0; s < 4; ++s) {
            if (ok[s]) {
                int ba = (rec[s] >> 17) * ACCS2 + 4 * l8;
                atomicAdd(&acc[ba + 0], qpacks(p[s].x, sc[s]));
                atomicAdd(&acc[ba + 1], qpacks(p[s].y, sc[s]));
                atomicAdd(&acc[ba + 2], qpacks(p[s].z, sc[s]));
                atomicAdd(&acc[ba + 3], qpacks(p[s].w, sc[s]));
            }
        }
    }
    __syncthreads();

    // writeout: wave w handles node-locals [w*16, w*16+16); lane = channel c.
    // channel c lives in 32-bit half (c&1) of u64 slot (c>>1). Bias removal
    // uses the per-node edge count qcnt (binprep4).
    const unsigned int* acc32 = (const unsigned int*)acc;
    float bc = b[lane];
    int half = lane & 1, slot = lane >> 1;
#pragma unroll 4
    for (int r = 0; r < 16; ++r) {
        int nl = wid * 16 + r;
        int node = blk * NPB + nl;
        if (node < N_NODES) {
            unsigned int raw = acc32[(nl * ACCS2 + slot) * 2 + half];
            int qsum = (int)(raw - (unsigned int)qcnt[node] * QBIAS_U);
            float di = dis[node] * INV_QSCALE;
            out[(size_t)node * OUT_CH + lane] = (float)qsum * di + bc;
        }
    }
}

extern "C" void kernel_launch(void* const* d_in, const int* in_sizes, int n_in,
                              void* d_out, int out_size, void* d_ws, size_t ws_size,
                              hipStream_t stream) {
    const float* x  = (const float*)d_in[0];
    const int*   ei = (const int*)d_in[1];
    const float* ew = (const float*)d_in[2];
    const float* W  = (const float*)d_in[3];
    const float* b  = (const float*)d_in[4];
    float* out = (float*)d_out;

    // Workspace layout (4-byte units)
    unsigned int* hs = (unsigned int*)d_ws;                   // N*32 uints (12.8 MB)
    unsigned int* Wb = hs + (size_t)N_NODES * 32;             // 4096 uints
    int* lscan2d = (int*)(Wb + 4096);                         // NB1*LSTRIDE ints (1.2 MB)
    int* mtot    = lscan2d + (size_t)NB1 * LSTRIDE;           // NBINS (pad 800)
    float* dis   = (float*)(mtot + 800);                      // N floats
    int* qcnt    = (int*)(dis + N_NODES);                     // N ints
    int* brec2   = qcnt + N_NODES;                            // NBINS*RECCAP ints (6.4 MB)
    int2* brec   = (int2*)(brec2 + (size_t)NBINS * RECCAP);   // NB1*CH1 int2 (10 MB)
    (void)ws_size; (void)in_sizes; (void)n_in; (void)out_size;

    sort_kernel<<<NB1 + 2, B1T, 0, stream>>>(ei, ew, W, Wb, lscan2d, brec);
    prep_gemm_kernel<<<NG4 + GEMM_BLOCKS, 512, 0, stream>>>(x, Wb, lscan2d, brec,
                                                            brec2, dis, qcnt,
                                                            mtot, hs);
    gather_kernel<<<NBINS, 512, 0, stream>>>(mtot, brec2, (const uint4*)hs,
                                             dis, qcnt, b, out);
}